// Round 6
// baseline (125.033 us; speedup 1.0000x reference)
//
#include <hip/hip_runtime.h>
#include <math.h>

#define NB 32
#define NL 2048
#define NH 8
#define NE 64
#define NM 64
#define MRI 128          // 2*NM rows (re stacked over im)
#define KS 4             // K-split for dft grid
#define BKA 64           // K-chunk for dft

typedef __attribute__((ext_vector_type(8))) __bf16 bf16x8;
typedef __attribute__((ext_vector_type(2))) __bf16 bf16x2;
typedef __attribute__((ext_vector_type(8))) unsigned short us8;
typedef __attribute__((ext_vector_type(4))) float f32x4;
typedef __attribute__((ext_vector_type(16))) float f32x16;

// fp32 -> bf16 RNE (scalar, table build)
__device__ __forceinline__ unsigned short f2bf(float x) {
  unsigned int u = __builtin_bit_cast(unsigned int, x);
  u = (u + 0x7fffu + ((u >> 16) & 1u)) >> 16;
  return (unsigned short)u;
}

// pack two f32 -> u32 of 2 bf16 (v_cvt_pk_bf16_f32)
__device__ __forceinline__ unsigned int pk2(float lo, float hi) {
  bf16x2 v;
  v[0] = (__bf16)lo;
  v[1] = (__bf16)hi;
  return __builtin_bit_cast(unsigned int, v);
}

__device__ __forceinline__ void gll16(const void* g, void* l) {
  __builtin_amdgcn_global_load_lds(
      (const __attribute__((address_space(1))) void*)g,
      (__attribute__((address_space(3))) void*)l, 16, 0, 0);
}

// ---------------- tables ----------------
// T  [128][2048] bf16 : row m = cos(2pi*f_m*l/L); row 64+m = -sin(...)
// IT [2048][128] bf16 : col m = scale_m*cos(2pi*m*l'/L); col 64+m = -scale_m*sin(...)
__global__ void tables_k(const int* __restrict__ idx, unsigned short* __restrict__ T,
                         unsigned short* __restrict__ IT) {
  int gid = blockIdx.x * blockDim.x + threadIdx.x;  // 0..262143
  const float w0 = 6.283185307179586f / (float)NL;
  {
    int row = gid >> 11, l = gid & (NL - 1);
    int m = row & 63;
    int f = idx[m];
    float th = (float)((f * l) & (NL - 1)) * w0;
    float s, c;
    sincosf(th, &s, &c);
    T[gid] = f2bf(row < 64 ? c : -s);
  }
  {
    int lp = gid >> 7, k = gid & 127;
    int m = k & 63;
    float th = (float)((m * lp) & (NL - 1)) * w0;
    float s, c;
    sincosf(th, &s, &c);
    float v;
    if (k < 64) v = ((m == 0 ? 1.0f : 2.0f) / (float)NL) * c;
    else        v = (m == 0 ? 0.0f : (-2.0f / (float)NL) * s);
    IT[gid] = f2bf(v);
  }
}

// ---------------- stage A: X = T * q (bf16 MFMA, fp32 acc) ----------------
// grid: (b*8+h)*KS+s = 1024 blocks; 256 thr = 4 waves; C tile [128 m_ri][64 e], K=512.
// LDS 50.4 KB -> 3 blocks/CU (12 waves/CU) for q-stream latency hiding.
__global__ __launch_bounds__(256) void dft_k(const float* __restrict__ q,
                                             const unsigned short* __restrict__ T,
                                             float* __restrict__ X2) {
  int bid = blockIdx.x;
  int s = bid & (KS - 1), h = (bid >> 2) & 7, b = bid >> 5;
  int t = threadIdx.x, lane = t & 63, wid = t >> 6;
  int mh = wid >> 1, eh = wid & 1;
  __shared__ unsigned short Al[2][MRI * BKA];  // [row 128][k 64], rows 128B, XOR (row&7)<<4
  __shared__ unsigned short Bl[2][NE * 72];    // [e 64][l 64 + pad], rows 144B, no XOR
  const float* qb = q + ((size_t)b * NL * NH + h) * NE;  // q[b][l][h][e]
  int k0b = s * (NL / KS);
  int eq = t >> 4;        // e-quad 0..15
  int lq = t & 15;        // l-quad 0..15
  f32x4 acc[4][2] = {};
  f32x4 st[4];

  auto stageA = [&](int bufi, int k0) {
#pragma unroll
    for (int n = 0; n < 4; ++n) {
      int lin = n * 4096 + wid * 1024 + lane * 16;
      int row = lin >> 7;
      int colb = (lin & 127) ^ ((row & 7) << 4);   // pre-swizzled global source
      gll16((const char*)T + (size_t)row * (NL * 2) + (size_t)k0 * 2 + colb,
            (char*)&Al[bufi][0] + n * 4096 + wid * 1024);
    }
  };
  auto loads = [&](int c) {
#pragma unroll
    for (int p = 0; p < 4; ++p)
      st[p] = *(const f32x4*)(qb + (size_t)(k0b + c * 64 + lq * 4 + p) * (NH * NE) + eq * 4);
  };
  auto writes = [&](int bufi) {
    char* base = (char*)&Bl[bufi][0];
#pragma unroll
    for (int j = 0; j < 4; ++j) {
      int e = eq * 4 + j;
      unsigned int w0 = pk2(st[0][j], st[1][j]);
      unsigned int w1 = pk2(st[2][j], st[3][j]);
      *(uint2*)(base + e * 144 + lq * 8) = make_uint2(w0, w1);  // conflict-free
    }
  };
  auto compute = [&](int bufi) {
    const char* ab = (const char*)&Al[bufi][0];
    const char* bb = (const char*)&Bl[bufi][0];
#pragma unroll
    for (int ks2 = 0; ks2 < 2; ++ks2) {
      bf16x8 bfr[2];
#pragma unroll
      for (int fn = 0; fn < 2; ++fn) {
        int e = eh * 32 + fn * 16 + (lane & 15);
        int off = e * 144 + ks2 * 64 + (lane >> 4) * 16;
        bfr[fn] = __builtin_bit_cast(bf16x8, *(const us8*)(bb + off));
      }
#pragma unroll
      for (int fm = 0; fm < 4; ++fm) {
        int row = mh * 64 + fm * 16 + (lane & 15);
        int off = ((row << 7) + (ks2 << 6) + ((lane >> 4) << 4)) ^ ((row & 7) << 4);
        bf16x8 afr = __builtin_bit_cast(bf16x8, *(const us8*)(ab + off));
#pragma unroll
        for (int fn = 0; fn < 2; ++fn)
          acc[fm][fn] = __builtin_amdgcn_mfma_f32_16x16x32_bf16(afr, bfr[fn], acc[fm][fn], 0, 0, 0);
      }
    }
  };

  stageA(0, k0b);
  loads(0);
  writes(0);
  __syncthreads();
  const int NCH = (NL / KS) / BKA;  // 8
  for (int c = 0; c < NCH; ++c) {
    int cur = c & 1;
    bool more = (c + 1) < NCH;
    if (more) {
      stageA(cur ^ 1, k0b + (c + 1) * BKA);
      loads(c + 1);
    }
    compute(cur);
    if (more) writes(cur ^ 1);
    __syncthreads();
  }
  // X2[bid][128][64] fp32 ; 16x16 C frag: col=lane&15, row=(lane>>4)*4+reg
  float* Xo = X2 + (size_t)bid * (MRI * NE);
#pragma unroll
  for (int fm = 0; fm < 4; ++fm)
#pragma unroll
    for (int fn = 0; fn < 2; ++fn)
#pragma unroll
      for (int r4 = 0; r4 < 4; ++r4) {
        int row = mh * 64 + fm * 16 + (lane >> 4) * 4 + r4;
        int col = eh * 32 + fn * 16 + (lane & 15);
        Xo[row * NE + col] = acc[fm][fn][r4];
      }
}

// ---------------- stage B: complex mix, fp32, m-pair blocks, 512 thr ----------------
// 256 blocks, 512 thr (8 waves/CU at 1 block/CU). XCD-swizzled: XCD k owns h=k.
__global__ __launch_bounds__(512) void mix_k(const float* __restrict__ X2,
                                             const float* __restrict__ wr,
                                             const float* __restrict__ wi,
                                             unsigned short* __restrict__ O) {
  int logical = (blockIdx.x & 7) * 32 + (blockIdx.x >> 3);  // bijective (256 % 8 == 0)
  int h = logical >> 5;
  int m0 = (logical & 31) * 2;
  __shared__ float Ws[2][2][64][64];   // [m'][ri][i][o] f32, 64 KB
  __shared__ float Xs[2][2][32][66];   // [m'][ri][b][i(+pad)] f32, 33.8 KB
  int t = threadIdx.x;
  // stage W: float2 over the m-pair (m innermost in w)
  for (int rep = 0; rep < 8; ++rep) {
    int id = rep * 512 + t;            // (i,o) over 4096
    int i = id >> 6, o = id & 63;
    size_t off = (((size_t)(h * 64 + i) * 64 + o) * 64 + m0);
    float2 vr = *(const float2*)(wr + off);
    float2 vi_ = *(const float2*)(wi + off);
    Ws[0][0][i][o] = vr.x;  Ws[1][0][i][o] = vr.y;
    Ws[0][1][i][o] = vi_.x; Ws[1][1][i][o] = vi_.y;
  }
  // stage X: f32x4 over i, summing the KS K-splits
  for (int rep = 0; rep < 2; ++rep) {
    int id = rep * 512 + t;            // mp(2) x bb(32) x iq(16) = 1024
    int mp = id >> 9, bb = (id >> 4) & 31, iq = id & 15;
    size_t base = ((size_t)(bb * 8 + h) * KS) * (MRI * NE);
    f32x4 xr = {0.f, 0.f, 0.f, 0.f}, xi = {0.f, 0.f, 0.f, 0.f};
#pragma unroll
    for (int sp = 0; sp < KS; ++sp) {
      size_t sb = base + (size_t)sp * (MRI * NE);
      xr += *(const f32x4*)(X2 + sb + (size_t)(m0 + mp) * NE + iq * 4);
      xi += *(const f32x4*)(X2 + sb + (size_t)(64 + m0 + mp) * NE + iq * 4);
    }
    *(f32x4*)&Xs[mp][0][bb][iq * 4] = xr;
    *(f32x4*)&Xs[mp][1][bb][iq * 4] = xi;
  }
  __syncthreads();
  int o0 = (t & 15) * 4, bb = t >> 4;  // thread: 1 b, 4 o, both m'
  float ar[2][4] = {{0.f}}, ai[2][4] = {{0.f}};
  for (int i = 0; i < 64; ++i) {
#pragma unroll
    for (int mp = 0; mp < 2; ++mp) {
      f32x4 wvr = *(const f32x4*)&Ws[mp][0][i][o0];
      f32x4 wvi = *(const f32x4*)&Ws[mp][1][i][o0];
      float xr = Xs[mp][0][bb][i], xi = Xs[mp][1][bb][i];
#pragma unroll
      for (int k2 = 0; k2 < 4; ++k2) {
        ar[mp][k2] += xr * wvr[k2] - xi * wvi[k2];
        ai[mp][k2] += xr * wvi[k2] + xi * wvr[k2];
      }
    }
  }
#pragma unroll
  for (int k2 = 0; k2 < 4; ++k2) {
    size_t ob = (((size_t)bb * 8 + h) * 64 + (o0 + k2)) * MRI;
    *(unsigned int*)(O + ob + m0) = pk2(ar[0][k2], ar[1][k2]);       // re pair
    *(unsigned int*)(O + ob + 64 + m0) = pk2(ai[0][k2], ai[1][k2]);  // im pair
  }
}

// ---------------- stage C: out = O * IT^T (bf16 MFMA, fp32 acc) ----------------
// grid: b(32) x rowtile(4) x coltile(16); block tile [128 (h,o)][128 l'], K=128
__global__ __launch_bounds__(256) void idft_k(const unsigned short* __restrict__ O,
                                              const unsigned short* __restrict__ IT,
                                              float* __restrict__ out) {
  int bid = blockIdx.x;
  int ct = bid & 15, rt = (bid >> 4) & 3, b = bid >> 6;
  int t = threadIdx.x, lane = t & 63, wid = t >> 6;
  __shared__ unsigned short Als[128 * 128];  // O rows 256B, swizzled
  __shared__ unsigned short Bls[128 * 128];  // ITt rows 256B, swizzled
  const unsigned short* Og = O + ((size_t)b * 512 + rt * 128) * MRI;
  const unsigned short* Ig = IT + (size_t)ct * 128 * MRI;
#pragma unroll
  for (int n = 0; n < 8; ++n) {
    int lin = n * 4096 + wid * 1024 + lane * 16;
    int row = lin >> 8;
    int colb = (lin & 255) ^ ((row & 7) << 4);
    gll16((const char*)Og + (size_t)row * 256 + colb, (char*)Als + n * 4096 + wid * 1024);
  }
#pragma unroll
  for (int n = 0; n < 8; ++n) {
    int lin = n * 4096 + wid * 1024 + lane * 16;
    int row = lin >> 8;
    int colb = (lin & 255) ^ ((row & 7) << 4);
    gll16((const char*)Ig + (size_t)row * 256 + colb, (char*)Bls + n * 4096 + wid * 1024);
  }
  __syncthreads();
  int wr2 = (wid >> 1) * 64, wc = (wid & 1) * 64;
  f32x16 acc[2][2] = {};
#pragma unroll
  for (int ksp = 0; ksp < 8; ++ksp) {
    bf16x8 af[2], bfv[2];
#pragma unroll
    for (int i2 = 0; i2 < 2; ++i2) {
      int row = wr2 + i2 * 32 + (lane & 31);
      int off = ((row << 8) + (ksp << 5) + ((lane >> 5) << 4)) ^ ((row & 7) << 4);
      af[i2] = __builtin_bit_cast(bf16x8, *(const us8*)((const char*)Als + off));
      int nr = wc + i2 * 32 + (lane & 31);
      int off2 = ((nr << 8) + (ksp << 5) + ((lane >> 5) << 4)) ^ ((nr & 7) << 4);
      bfv[i2] = __builtin_bit_cast(bf16x8, *(const us8*)((const char*)Bls + off2));
    }
#pragma unroll
    for (int i2 = 0; i2 < 2; ++i2)
#pragma unroll
      for (int j2 = 0; j2 < 2; ++j2)
        acc[i2][j2] = __builtin_amdgcn_mfma_f32_32x32x16_bf16(af[i2], bfv[j2], acc[i2][j2], 0, 0, 0);
  }
  // 32x32 C frag: col=lane&31, row=(reg&3)+8*(reg>>2)+4*(lane>>5)
  float* ob = out + ((size_t)b * 512 + rt * 128) * NL + ct * 128;
#pragma unroll
  for (int i2 = 0; i2 < 2; ++i2)
#pragma unroll
    for (int j2 = 0; j2 < 2; ++j2)
#pragma unroll
      for (int rg = 0; rg < 16; ++rg) {
        int row = wr2 + i2 * 32 + ((rg & 3) + 8 * (rg >> 2) + 4 * (lane >> 5));
        int col = wc + j2 * 32 + (lane & 31);
        ob[(size_t)row * NL + col] = acc[i2][j2][rg];
      }
}

extern "C" void kernel_launch(void* const* d_in, const int* in_sizes, int n_in,
                              void* d_out, int out_size, void* d_ws, size_t ws_size,
                              hipStream_t stream) {
  const float* q = (const float*)d_in[0];
  const float* wr = (const float*)d_in[3];
  const float* wi = (const float*)d_in[4];
  const int* idx = (const int*)d_in[5];
  float* out = (float*)d_out;
  char* ws = (char*)d_ws;

  constexpr size_t TBYTES = (size_t)MRI * NL * 2;              // 512 KB each table
  constexpr size_t X2ELEM = (size_t)NB * NH * KS * MRI * NE;   // 8,388,608 f32
  constexpr size_t OELEM = (size_t)NB * NH * NE * MRI;         // 2,097,152 bf16
  constexpr size_t NEED = 2 * TBYTES + X2ELEM * 4 + OELEM * 2;
  if (ws_size < NEED) return;

  unsigned short* T = (unsigned short*)ws;
  unsigned short* IT = (unsigned short*)(ws + TBYTES);
  float* X2 = (float*)(ws + 2 * TBYTES);
  unsigned short* O = (unsigned short*)(ws + 2 * TBYTES + X2ELEM * 4);

  hipLaunchKernelGGL(tables_k, dim3(1024), dim3(256), 0, stream, idx, T, IT);
  hipLaunchKernelGGL(dft_k, dim3(NB * NH * KS), dim3(256), 0, stream, q, T, X2);
  hipLaunchKernelGGL(mix_k, dim3(256), dim3(512), 0, stream, X2, wr, wi, O);
  hipLaunchKernelGGL(idft_k, dim3(NB * 4 * 16), dim3(256), 0, stream, O, IT, out);
}

// Round 7
// 96.346 us; speedup vs baseline: 1.2977x; 1.2977x over previous
//
#include <hip/hip_runtime.h>
#include <math.h>

#define NB 32
#define NL 2048
#define NH 8
#define NE 64
#define NM 64
#define MRI 128          // 2*NM (re stacked over im)

typedef __attribute__((ext_vector_type(8))) __bf16 bf16x8;
typedef __attribute__((ext_vector_type(2))) __bf16 bf16x2;
typedef __attribute__((ext_vector_type(8))) unsigned short us8;
typedef __attribute__((ext_vector_type(4))) float f32x4;
typedef __attribute__((ext_vector_type(16))) float f32x16;

__device__ __forceinline__ unsigned short f2bf(float x) {
  unsigned int u = __builtin_bit_cast(unsigned int, x);
  u = (u + 0x7fffu + ((u >> 16) & 1u)) >> 16;
  return (unsigned short)u;
}
__device__ __forceinline__ float bf2f(unsigned short u) {
  return __builtin_bit_cast(float, (unsigned int)u << 16);
}
__device__ __forceinline__ unsigned int pk2(float lo, float hi) {
  bf16x2 v;
  v[0] = (__bf16)lo;
  v[1] = (__bf16)hi;
  return __builtin_bit_cast(unsigned int, v);
}
__device__ __forceinline__ void gll16(const void* g, void* l) {
  __builtin_amdgcn_global_load_lds(
      (const __attribute__((address_space(1))) void*)g,
      (__attribute__((address_space(3))) void*)l, 16, 0, 0);
}

// ---------------- tables + W->bf16 ----------------
// T  [128][2048] bf16 : row m = cos(2pi*f_m*l/L); row 64+m = -sin(...)
// IT [2048][128] bf16 : col m = s_m*cos(2pi*m*l'/L); col 64+m = -s_m*sin(...)
// WB r/i : w_real/imag [h][i][o][m] converted to bf16, same layout.
__global__ void tables_k(const int* __restrict__ idx,
                         const float* __restrict__ wr, const float* __restrict__ wi,
                         unsigned short* __restrict__ T, unsigned short* __restrict__ IT,
                         unsigned short* __restrict__ WBr, unsigned short* __restrict__ WBi) {
  int gid = blockIdx.x * blockDim.x + threadIdx.x;  // 0..262143
  const float w0 = 6.283185307179586f / (float)NL;
  {
    int row = gid >> 11, l = gid & (NL - 1);
    int m = row & 63;
    int f = idx[m];
    float s, c;
    sincosf((float)((f * l) & (NL - 1)) * w0, &s, &c);
    T[gid] = f2bf(row < 64 ? c : -s);
  }
  {
    int lp = gid >> 7, k = gid & 127;
    int m = k & 63;
    float s, c;
    sincosf((float)((m * lp) & (NL - 1)) * w0, &s, &c);
    float v = (k < 64) ? ((m == 0 ? 1.0f : 2.0f) / (float)NL) * c
                       : (m == 0 ? 0.0f : (-2.0f / (float)NL) * s);
    IT[gid] = f2bf(v);
  }
  {
    const float2* wr2 = (const float2*)wr;
    const float2* wi2 = (const float2*)wi;
    unsigned int* obr = (unsigned int*)WBr;
    unsigned int* obi = (unsigned int*)WBi;
#pragma unroll
    for (int r = 0; r < 4; ++r) {           // 4*262144 = 1,048,576 float2 per comp
      int j = r * 262144 + gid;
      float2 a = wr2[j];
      float2 b2 = wi2[j];
      obr[j] = pk2(a.x, a.y);
      obi[j] = pk2(b2.x, b2.y);
    }
  }
}

// ---------------- fused per-(b,h) kernel ----------------
// 256 blocks x 512 thr. P1: X = T*q (MFMA, K=2048) -> Xs LDS fp32.
// P2: complex mix (VALU fp32, W bf16 from L2) -> Ot LDS bf16 [64 o][128 m_ri].
// P3: out = Ot * IT^T (MFMA, A hoisted from LDS, B direct from L2).
__global__ __launch_bounds__(512) void fused_k(const float* __restrict__ q,
                                               const unsigned short* __restrict__ T,
                                               const unsigned short* __restrict__ IT,
                                               const unsigned short* __restrict__ WBr,
                                               const unsigned short* __restrict__ WBi,
                                               float* __restrict__ out) {
  __shared__ __align__(16) char smem[51200];
  int t = threadIdx.x, lane = t & 63, wid = t >> 6;
  int h = blockIdx.x & 7, b = blockIdx.x >> 3;

  // ================= P1: DFT =================
  {
    unsigned short* Al = (unsigned short*)smem;  // dbuf 2 x 16384 B, 128B rows, XOR (row&7)<<4
    char* Bl = smem + 32768;                     // dbuf 2 x 9216 B, [e 64][l 64] rows 144B
    const float* qb = q + ((size_t)b * NL * NH + h) * NE;  // q[b][l][h][e]
    int mh = wid >> 1, eh = wid & 1;
    int ts = t & 255;
    int eq = ts >> 4, lq = ts & 15;
    bool stagerB = (wid < 4);   // waves 0-3: q staging; waves 4-7: T gll16
    f32x4 acc[2][2] = {};
    f32x4 st[4];

    auto stageA = [&](int bufi, int k0) {
      int t2 = t - 256;
#pragma unroll
      for (int n = 0; n < 4; ++n) {
        int lin = n * 4096 + t2 * 16;
        int row = lin >> 7;
        int colb = (lin & 127) ^ ((row & 7) << 4);   // pre-swizzled source
        gll16((const char*)T + (size_t)row * (NL * 2) + (size_t)k0 * 2 + colb,
              (char*)Al + bufi * 16384 + lin);
      }
    };
    auto loadsB = [&](int c) {
#pragma unroll
      for (int p = 0; p < 4; ++p)
        st[p] = *(const f32x4*)(qb + (size_t)(c * 64 + lq * 4 + p) * (NH * NE) + eq * 4);
    };
    auto writesB = [&](int bufi) {
      char* base = Bl + bufi * 9216;
#pragma unroll
      for (int j = 0; j < 4; ++j) {
        int e = eq * 4 + j;
        unsigned int w0 = pk2(st[0][j], st[1][j]);
        unsigned int w1 = pk2(st[2][j], st[3][j]);
        *(uint2*)(base + e * 144 + lq * 8) = make_uint2(w0, w1);
      }
    };
    auto compute = [&](int bufi) {
      const char* ab = (const char*)Al + bufi * 16384;
      const char* bb = Bl + bufi * 9216;
#pragma unroll
      for (int ks2 = 0; ks2 < 2; ++ks2) {
        bf16x8 bfr[2];
#pragma unroll
        for (int fn = 0; fn < 2; ++fn) {
          int e = eh * 32 + fn * 16 + (lane & 15);
          bfr[fn] = __builtin_bit_cast(
              bf16x8, *(const us8*)(bb + e * 144 + ks2 * 64 + (lane >> 4) * 16));
        }
#pragma unroll
        for (int fm = 0; fm < 2; ++fm) {
          int row = mh * 32 + fm * 16 + (lane & 15);
          int off = ((row << 7) + (ks2 << 6) + ((lane >> 4) << 4)) ^ ((row & 7) << 4);
          bf16x8 afr = __builtin_bit_cast(bf16x8, *(const us8*)(ab + off));
          acc[fm][0] = __builtin_amdgcn_mfma_f32_16x16x32_bf16(afr, bfr[0], acc[fm][0], 0, 0, 0);
          acc[fm][1] = __builtin_amdgcn_mfma_f32_16x16x32_bf16(afr, bfr[1], acc[fm][1], 0, 0, 0);
        }
      }
    };

    if (stagerB) { loadsB(0); writesB(0); } else { stageA(0, 0); }
    __syncthreads();
    for (int c = 0; c < 32; ++c) {
      int cur = c & 1;
      bool more = (c + 1) < 32;
      if (more) {
        if (stagerB) loadsB(c + 1);
        else stageA(cur ^ 1, (c + 1) * 64);
      }
      compute(cur);
      if (more && stagerB) writesB(cur ^ 1);
      __syncthreads();
    }
    // acc -> Xs fp32 [128 m_ri][68 f32 rows=272B], XOR ((row>>3)&7)<<4
#pragma unroll
    for (int fm = 0; fm < 2; ++fm)
#pragma unroll
      for (int fn = 0; fn < 2; ++fn)
#pragma unroll
        for (int r4 = 0; r4 < 4; ++r4) {
          int row = mh * 32 + fm * 16 + (lane >> 4) * 4 + r4;
          int col = eh * 32 + fn * 16 + (lane & 15);
          int off = (row * 272 + col * 4) ^ (((row >> 3) & 7) << 4);
          *(float*)(smem + off) = acc[fm][fn][r4];
        }
  }
  __syncthreads();

  // ================= P2: mix (fp32 VALU, bf16 W) =================
  {
    char* OtB = smem + 34816;           // [64 o][128 m_ri] bf16, 256B rows, XOR (o&7)<<4
    int o = t >> 3, mq = t & 7;         // thread: 1 o, 8 m (m = mq*8+mi)
    const unsigned short* wbr = WBr + (size_t)h * 262144 + (size_t)o * 64 + mq * 8;
    const unsigned short* wbi = WBi + (size_t)h * 262144 + (size_t)o * 64 + mq * 8;
    float orr[8] = {}, oii[8] = {};
    for (int ib = 0; ib < 16; ++ib) {
      f32x4 xr4[8], xi4[8];
#pragma unroll
      for (int mi = 0; mi < 8; ++mi) {
        int m = mq * 8 + mi;
        xr4[mi] = *(const f32x4*)(smem + ((m * 272 + ib * 16) ^ (mq << 4)));
        xi4[mi] = *(const f32x4*)(smem + (((64 + m) * 272 + ib * 16) ^ (mq << 4)));
      }
      us8 wr8[4], wi8[4];
#pragma unroll
      for (int ii = 0; ii < 4; ++ii) {
        int i = ib * 4 + ii;
        wr8[ii] = *(const us8*)(wbr + (size_t)i * 4096);
        wi8[ii] = *(const us8*)(wbi + (size_t)i * 4096);
      }
#pragma unroll
      for (int ii = 0; ii < 4; ++ii)
#pragma unroll
        for (int mi = 0; mi < 8; ++mi) {
          float wrv = bf2f(wr8[ii][mi]);
          float wiv = bf2f(wi8[ii][mi]);
          orr[mi] += xr4[mi][ii] * wrv - xi4[mi][ii] * wiv;
          oii[mi] += xr4[mi][ii] * wiv + xi4[mi][ii] * wrv;
        }
    }
    uint4 vr = make_uint4(pk2(orr[0], orr[1]), pk2(orr[2], orr[3]),
                          pk2(orr[4], orr[5]), pk2(orr[6], orr[7]));
    uint4 vi = make_uint4(pk2(oii[0], oii[1]), pk2(oii[2], oii[3]),
                          pk2(oii[4], oii[5]), pk2(oii[6], oii[7]));
    *(uint4*)(OtB + ((o * 256 + mq * 16) ^ ((o & 7) << 4))) = vr;
    *(uint4*)(OtB + ((o * 256 + 128 + mq * 16) ^ ((o & 7) << 4))) = vi;
  }
  __syncthreads();

  // ================= P3: iDFT =================
  {
    const char* OtB = smem + 34816;
    bf16x8 af[2][8];
#pragma unroll
    for (int rg2 = 0; rg2 < 2; ++rg2)
#pragma unroll
      for (int ks = 0; ks < 8; ++ks) {
        int row = rg2 * 32 + (lane & 31);
        int off = (row * 256 + ks * 32 + (lane >> 5) * 16) ^ ((row & 7) << 4);
        af[rg2][ks] = __builtin_bit_cast(bf16x8, *(const us8*)(OtB + off));
      }
    float* ob = out + ((size_t)(b * 8 + h) * 64) * NL;
    int l0 = wid * 256;
    for (int ct = 0; ct < 8; ++ct) {
      int lr = l0 + ct * 32 + (lane & 31);
      f32x16 a2[2] = {};
#pragma unroll
      for (int ks = 0; ks < 8; ++ks) {
        bf16x8 bv = __builtin_bit_cast(
            bf16x8, *(const us8*)(IT + (size_t)lr * MRI + ks * 16 + (lane >> 5) * 8));
        a2[0] = __builtin_amdgcn_mfma_f32_32x32x16_bf16(af[0][ks], bv, a2[0], 0, 0, 0);
        a2[1] = __builtin_amdgcn_mfma_f32_32x32x16_bf16(af[1][ks], bv, a2[1], 0, 0, 0);
      }
#pragma unroll
      for (int rg2 = 0; rg2 < 2; ++rg2)
#pragma unroll
        for (int rg = 0; rg < 16; ++rg) {
          int row = rg2 * 32 + ((rg & 3) + 8 * (rg >> 2) + 4 * (lane >> 5));
          ob[(size_t)row * NL + lr] = a2[rg2][rg];
        }
    }
  }
}

extern "C" void kernel_launch(void* const* d_in, const int* in_sizes, int n_in,
                              void* d_out, int out_size, void* d_ws, size_t ws_size,
                              hipStream_t stream) {
  const float* q = (const float*)d_in[0];
  const float* wr = (const float*)d_in[3];
  const float* wi = (const float*)d_in[4];
  const int* idx = (const int*)d_in[5];
  float* out = (float*)d_out;
  char* ws = (char*)d_ws;

  constexpr size_t TBYTES = (size_t)MRI * NL * 2;      // 512 KB per table
  constexpr size_t WBBYTES = (size_t)NH * NE * NE * NM * 2;  // 4 MB per comp
  constexpr size_t NEED = 2 * TBYTES + 2 * WBBYTES;
  if (ws_size < NEED) return;

  unsigned short* T = (unsigned short*)ws;
  unsigned short* IT = (unsigned short*)(ws + TBYTES);
  unsigned short* WBr = (unsigned short*)(ws + 2 * TBYTES);
  unsigned short* WBi = (unsigned short*)(ws + 2 * TBYTES + WBBYTES);

  hipLaunchKernelGGL(tables_k, dim3(1024), dim3(256), 0, stream, idx, wr, wi, T, IT, WBr, WBi);
  hipLaunchKernelGGL(fused_k, dim3(NB * NH), dim3(512), 0, stream, q, T, IT, WBr, WBi, out);
}